// Round 1
// baseline (603.393 us; speedup 1.0000x reference)
//
#include <hip/hip_runtime.h>
#include <math.h>

// ---------------- edge dtype sniff + decode ----------------
// If edge_index is int64 (values < 2^31), every odd 32-bit word is 0.
__global__ void k_detect(const int* __restrict__ ew, int* __restrict__ flag) {
    __shared__ int nz;
    if (threadIdx.x == 0) nz = 0;
    __syncthreads();
    int a = ew[2 * threadIdx.x + 1];
    int b = ew[512 + 2 * threadIdx.x + 1];
    if (a | b) atomicAdd(&nz, 1);
    __syncthreads();
    if (threadIdx.x == 0) *flag = (nz == 0) ? 1 : 0;
}

__global__ void k_convert(const int* __restrict__ ew, const int* __restrict__ flag,
                          int* __restrict__ src, int* __restrict__ dst, int E) {
    int e = blockIdx.x * blockDim.x + threadIdx.x;
    if (e >= E) return;
    if (*flag) {  // int64 storage
        src[e] = ew[2 * e];
        dst[e] = ew[2 * E + 2 * e];
    } else {      // int32 storage
        src[e] = ew[e];
        dst[e] = ew[E + e];
    }
}

// ---------------- CSR build (by dst) ----------------
__global__ void k_hist(const int* __restrict__ dst, int* __restrict__ deg, int E) {
    int e = blockIdx.x * blockDim.x + threadIdx.x;
    if (e < E) atomicAdd(&deg[dst[e]], 1);
}

__global__ __launch_bounds__(1024) void k_scan(const int* __restrict__ deg,
                                               int* __restrict__ rp, int N) {
    __shared__ int buf[1024];
    __shared__ int carry_s;
    int t = threadIdx.x;
    if (t == 0) carry_s = 0;
    __syncthreads();
    for (int base = 0; base < N; base += 1024) {
        int i = base + t;
        int v = (i < N) ? deg[i] : 0;
        buf[t] = v;
        __syncthreads();
        int x = v;
        for (int off = 1; off < 1024; off <<= 1) {
            int y = (t >= off) ? buf[t - off] : 0;
            __syncthreads();
            x += y;
            buf[t] = x;
            __syncthreads();
        }
        int c = carry_s;
        if (i < N) rp[i] = c + x - v;   // exclusive
        __syncthreads();
        if (t == 0) carry_s = c + buf[1023];
        __syncthreads();
    }
    if (t == 0) rp[N] = carry_s;
}

__global__ void k_copy(const int* __restrict__ a, int* __restrict__ b, int n) {
    int i = blockIdx.x * blockDim.x + threadIdx.x;
    if (i < n) b[i] = a[i];
}

__global__ void k_fill(const int* __restrict__ src, const int* __restrict__ dst,
                       int* __restrict__ cur, int* __restrict__ col, int E) {
    int e = blockIdx.x * blockDim.x + threadIdx.x;
    if (e < E) {
        int p = atomicAdd(&cur[dst[e]], 1);
        col[p] = src[e];
    }
}

__global__ void k_dinv(const int* __restrict__ deg, float* __restrict__ dinv, int N) {
    int i = blockIdx.x * blockDim.x + threadIdx.x;
    if (i < N) dinv[i] = rsqrtf((float)(deg[i] + 1));  // +1 self loop
}

// ---------------- matmul: H[N x D] = X[N x 128] @ W[128 x D] ----------------
template <int D>
__global__ __launch_bounds__(256) void k_mm(const float* __restrict__ X,
                                            const float* __restrict__ W,
                                            float* __restrict__ H, int N) {
    constexpr int TXN = D / 4;      // threads along cols (4 cols each)
    constexpr int TYN = 256 / TXN;  // row groups
    constexpr int RPT = 64 / TYN;   // rows per thread
    __shared__ float sW[64 * D];    // W chunk [64][D]
    __shared__ float sX[64][68];    // x^T chunk [k][r], pad 68 (272B rows, 16B aligned)
    const int t = threadIdx.x;
    const int r0 = blockIdx.x * 64;
    const int tx = t % TXN, ty = t / TXN;
    const int c0 = tx * 4, rr0 = ty * RPT;
    float acc[RPT][4];
#pragma unroll
    for (int i = 0; i < RPT; i++) acc[i][0] = acc[i][1] = acc[i][2] = acc[i][3] = 0.f;

    for (int k0 = 0; k0 < 128; k0 += 64) {
        __syncthreads();
        for (int idx = t; idx < 64 * D / 4; idx += 256)
            reinterpret_cast<float4*>(sW)[idx] =
                reinterpret_cast<const float4*>(W + (size_t)k0 * D)[idx];
        for (int idx = t; idx < 1024; idx += 256) {
            int r = idx & 63, kq = idx >> 6;   // lanes -> consecutive r: conflict-free LDS writes
            int gr = r0 + r;
            float4 v = make_float4(0.f, 0.f, 0.f, 0.f);
            if (gr < N) v = reinterpret_cast<const float4*>(X + (size_t)gr * 128 + k0)[kq];
            sX[kq * 4 + 0][r] = v.x;
            sX[kq * 4 + 1][r] = v.y;
            sX[kq * 4 + 2][r] = v.z;
            sX[kq * 4 + 3][r] = v.w;
        }
        __syncthreads();
#pragma unroll 4
        for (int kk = 0; kk < 64; kk++) {
            float4 wv = *reinterpret_cast<const float4*>(&sW[kk * D + c0]);
            float xr[RPT];
#pragma unroll
            for (int i = 0; i < RPT; i += 4) {
                float4 xv = *reinterpret_cast<const float4*>(&sX[kk][rr0 + i]);
                xr[i] = xv.x; xr[i + 1] = xv.y; xr[i + 2] = xv.z; xr[i + 3] = xv.w;
            }
#pragma unroll
            for (int i = 0; i < RPT; i++) {
                acc[i][0] = fmaf(xr[i], wv.x, acc[i][0]);
                acc[i][1] = fmaf(xr[i], wv.y, acc[i][1]);
                acc[i][2] = fmaf(xr[i], wv.z, acc[i][2]);
                acc[i][3] = fmaf(xr[i], wv.w, acc[i][3]);
            }
        }
    }
#pragma unroll
    for (int i = 0; i < RPT; i++) {
        int gr = r0 + rr0 + i;
        if (gr < N) {
            float4 v;
            v.x = acc[i][0]; v.y = acc[i][1]; v.z = acc[i][2]; v.w = acc[i][3];
            *reinterpret_cast<float4*>(H + (size_t)gr * D + c0) = v;
        }
    }
}

// ---------------- aggregation: out[i] = dinv[i]*(sum dinv[s]h[s] + dinv[i]h[i]) + b ----------------
template <int D>
__global__ __launch_bounds__(256) void k_agg(const float* __restrict__ H,
                                             const int* __restrict__ rp,
                                             const int* __restrict__ col,
                                             const float* __restrict__ dinv,
                                             const float* __restrict__ bias,
                                             float* __restrict__ out, int N) {
    int wv = threadIdx.x >> 6, lane = threadIdx.x & 63;
    int i = blockIdx.x * 4 + wv;
    if (i >= N) return;
    int e0 = rp[i], e1 = rp[i + 1];
    float di = dinv[i];
    float a0 = di * H[(size_t)i * D + lane];
    float a1 = 0.f;
    if (D == 128) a1 = di * H[(size_t)i * D + 64 + lane];
    for (int e = e0; e < e1; e++) {
        int s = col[e];
        float ds = dinv[s];
        const float* hs = H + (size_t)s * D;
        a0 += ds * hs[lane];
        if (D == 128) a1 += ds * hs[64 + lane];
    }
    float* o = out + (size_t)i * D;
    o[lane] = fmaf(di, a0, bias[lane]);
    if (D == 128) o[64 + lane] = fmaf(di, a1, bias[64 + lane]);
}

// ---------------- BN stats (column sum / sumsq) ----------------
__global__ __launch_bounds__(256) void k_stats(const float* __restrict__ X,
                                               float* __restrict__ S, int N) {
    int f = threadIdx.x & 127, h = threadIdx.x >> 7;
    int rend = min(N, (int)(blockIdx.x + 1) * 256);
    float s = 0.f, q = 0.f;
    for (int r = blockIdx.x * 256 + h; r < rend; r += 2) {
        float v = X[(size_t)r * 128 + f];
        s += v;
        q += v * v;
    }
    __shared__ float ls[256], lq[256];
    ls[threadIdx.x] = s;
    lq[threadIdx.x] = q;
    __syncthreads();
    if (h == 0) {
        atomicAdd(&S[f], ls[f] + ls[f + 128]);
        atomicAdd(&S[128 + f], lq[f] + lq[f + 128]);
    }
}

// ---------------- fused BN apply + ReLU (in place) ----------------
__global__ __launch_bounds__(256) void k_bnrelu(float* __restrict__ X,
                                                const float* __restrict__ S,
                                                const float* __restrict__ g,
                                                const float* __restrict__ be,
                                                int N, float invN) {
    int idx = blockIdx.x * blockDim.x + threadIdx.x;
    if (idx >= N * 32) return;
    int f4 = (idx & 31) * 4;
    float4 v = reinterpret_cast<float4*>(X)[idx];
    float* vv = &v.x;
#pragma unroll
    for (int j = 0; j < 4; j++) {
        int f = f4 + j;
        float m = S[f] * invN;
        float var = fmaf(-m, m, S[128 + f] * invN);
        float rstd = rsqrtf(var + 1e-5f);
        vv[j] = fmaxf(0.f, fmaf(g[f] * rstd, vv[j] - m, be[f]));
    }
    reinterpret_cast<float4*>(X)[idx] = v;
}

// ---------------- launch ----------------
extern "C" void kernel_launch(void* const* d_in, const int* in_sizes, int n_in,
                              void* d_out, int out_size, void* d_ws, size_t ws_size,
                              hipStream_t stream) {
    const float* x   = (const float*)d_in[0];
    const int*   ew  = (const int*)d_in[1];
    const float* W1  = (const float*)d_in[2];
    const float* b1  = (const float*)d_in[3];
    const float* g1  = (const float*)d_in[4];
    const float* be1 = (const float*)d_in[5];
    const float* W2  = (const float*)d_in[6];
    const float* b2  = (const float*)d_in[7];
    const float* g2  = (const float*)d_in[8];
    const float* be2 = (const float*)d_in[9];
    const float* W3  = (const float*)d_in[10];
    const float* b3  = (const float*)d_in[11];
    const int N = in_sizes[0] / 128;
    const int E = in_sizes[1] / 2;

    char* w = (char*)d_ws;
    size_t off = 0;
    auto alloc = [&](size_t bytes) -> char* {
        char* p = w + off;
        off = (off + bytes + 255) & ~(size_t)255;
        return p;
    };
    int*   src  = (int*)alloc((size_t)E * 4);
    int*   dst  = (int*)alloc((size_t)E * 4);
    int*   col  = (int*)alloc((size_t)E * 4);
    int*   deg  = (int*)alloc((size_t)N * 4);
    int*   rp   = (int*)alloc((size_t)(N + 1) * 4);
    int*   cur  = (int*)alloc((size_t)N * 4);
    float* dinv = (float*)alloc((size_t)N * 4);
    float* S    = (float*)alloc(1024);
    int*   flag = (int*)alloc(256);
    float* h    = (float*)alloc((size_t)N * 128 * 4);
    float* t    = (float*)alloc((size_t)N * 128 * 4);
    (void)ws_size; (void)n_in; (void)out_size;

    const int gE = (E + 255) / 256;
    const int gN = (N + 255) / 256;
    const int gM = (N + 63) / 64;
    const int gA = (N + 3) / 4;
    const int gS = (N + 255) / 256;
    const int gB = (N * 32 + 255) / 256;
    const float invN = 1.0f / (float)N;

    hipMemsetAsync(deg, 0, (size_t)N * 4, stream);
    k_detect<<<1, 256, 0, stream>>>(ew, flag);
    k_convert<<<gE, 256, 0, stream>>>(ew, flag, src, dst, E);
    k_hist<<<gE, 256, 0, stream>>>(dst, deg, E);
    k_scan<<<1, 1024, 0, stream>>>(deg, rp, N);
    k_copy<<<gN, 256, 0, stream>>>(rp, cur, N);
    k_fill<<<gE, 256, 0, stream>>>(src, dst, cur, col, E);
    k_dinv<<<gN, 256, 0, stream>>>(deg, dinv, N);

    // layer 1
    k_mm<128><<<gM, 256, 0, stream>>>(x, W1, h, N);
    k_agg<128><<<gA, 256, 0, stream>>>(h, rp, col, dinv, b1, t, N);
    hipMemsetAsync(S, 0, 1024, stream);
    k_stats<<<gS, 256, 0, stream>>>(t, S, N);
    k_bnrelu<<<gB, 256, 0, stream>>>(t, S, g1, be1, N, invN);

    // layer 2
    k_mm<128><<<gM, 256, 0, stream>>>(t, W2, h, N);
    k_agg<128><<<gA, 256, 0, stream>>>(h, rp, col, dinv, b2, t, N);
    hipMemsetAsync(S, 0, 1024, stream);
    k_stats<<<gS, 256, 0, stream>>>(t, S, N);
    k_bnrelu<<<gB, 256, 0, stream>>>(t, S, g2, be2, N, invN);

    // layer 3 (D_OUT = 64), bias fused, straight to d_out
    k_mm<64><<<gM, 256, 0, stream>>>(t, W3, h, N);
    k_agg<64><<<gA, 256, 0, stream>>>(h, rp, col, dinv, b3, (float*)d_out, N);
}

// Round 2
// 412.969 us; speedup vs baseline: 1.4611x; 1.4611x over previous
//
#include <hip/hip_runtime.h>
#include <math.h>

// ---------------- edge dtype sniff ----------------
__global__ void k_detect(const int* __restrict__ ew, int* __restrict__ flag) {
    __shared__ int nz;
    if (threadIdx.x == 0) nz = 0;
    __syncthreads();
    int a = ew[2 * threadIdx.x + 1];
    int b = ew[512 + 2 * threadIdx.x + 1];
    if (a | b) atomicAdd(&nz, 1);
    __syncthreads();
    if (threadIdx.x == 0) *flag = (nz == 0) ? 1 : 0;
}

// convert + degree histogram fused
__global__ void k_convert_hist(const int* __restrict__ ew, const int* __restrict__ flag,
                               int* __restrict__ src, int* __restrict__ dst,
                               int* __restrict__ deg, int E) {
    int e = blockIdx.x * blockDim.x + threadIdx.x;
    if (e >= E) return;
    int s, d;
    if (*flag) { s = ew[2 * e]; d = ew[2 * E + 2 * e]; }
    else       { s = ew[e];     d = ew[E + e]; }
    src[e] = s;
    dst[e] = d;
    atomicAdd(&deg[d], 1);
}

// ---------------- 3-phase parallel exclusive scan of deg -> rp ----------------
__global__ __launch_bounds__(1024) void k_scan1(const int* __restrict__ deg,
                                                int* __restrict__ rp,
                                                int* __restrict__ bsum, int N) {
    __shared__ int buf[1024];
    int t = threadIdx.x;
    int i = blockIdx.x * 1024 + t;
    int v = (i < N) ? deg[i] : 0;
    buf[t] = v;
    __syncthreads();
    int x = v;
    for (int off = 1; off < 1024; off <<= 1) {
        int y = (t >= off) ? buf[t - off] : 0;
        __syncthreads();
        x += y;
        buf[t] = x;
        __syncthreads();
    }
    if (i < N) rp[i] = x - v;                       // block-local exclusive
    if (t == 1023) bsum[blockIdx.x] = x;            // block total
}

__global__ void k_scan2(int* __restrict__ bsum, int* __restrict__ rp,
                        int nb, int N) {
    int lane = threadIdx.x;                          // 64 lanes, nb <= 64
    int v = (lane < nb) ? bsum[lane] : 0;
    int x = v;
    for (int off = 1; off < 64; off <<= 1) {
        int y = __shfl_up(x, off);
        if (lane >= off) x += y;
    }
    if (lane < nb) bsum[lane] = x - v;               // exclusive
    if (lane == 63) rp[N] = x;                       // total = E
}

__global__ void k_fixup(int* __restrict__ rp, int* __restrict__ cur,
                        const int* __restrict__ bsum, int N) {
    int i = blockIdx.x * blockDim.x + threadIdx.x;
    if (i < N) {
        int r = rp[i] + bsum[i >> 10];
        rp[i] = r;
        cur[i] = r;
    }
}

__global__ void k_fill(const int* __restrict__ src, const int* __restrict__ dst,
                       int* __restrict__ cur, int* __restrict__ col, int E) {
    int e = blockIdx.x * blockDim.x + threadIdx.x;
    if (e < E) {
        int p = atomicAdd(&cur[dst[e]], 1);
        col[p] = src[e];
    }
}

__global__ void k_dinv(const int* __restrict__ deg, float* __restrict__ dinv, int N) {
    int i = blockIdx.x * blockDim.x + threadIdx.x;
    if (i < N) dinv[i] = rsqrtf((float)(deg[i] + 1));  // +1 self loop
}

// ------- matmul: H[r][c] = dinv[r] * sum_k act(X[r][k]) * W[k][c] -------
// act = identity (FUSE=false) or BN+ReLU from stats S (FUSE=true)
template <int D, bool FUSE>
__global__ __launch_bounds__(256) void k_mm(const float* __restrict__ X,
                                            const float* __restrict__ W,
                                            float* __restrict__ H,
                                            const float* __restrict__ dinv,
                                            const float* __restrict__ S,
                                            const float* __restrict__ g,
                                            const float* __restrict__ be,
                                            int N, float invN) {
    constexpr int TXN = D / 4;      // threads along cols (4 cols each)
    constexpr int TYN = 256 / TXN;  // row groups
    constexpr int RPT = 64 / TYN;   // rows per thread
    __shared__ float sW[64 * D];    // W chunk [64][D]
    __shared__ float sX[64][68];    // x^T chunk [k][r], pad 68
    __shared__ float sAl[128], sBe[128];
    const int t = threadIdx.x;
    const int r0 = blockIdx.x * 64;
    const int tx = t % TXN, ty = t / TXN;
    const int c0 = tx * 4, rr0 = ty * RPT;

    if (FUSE) {
        if (t < 128) {
            float m = S[t] * invN;
            float var = fmaf(-m, m, S[128 + t] * invN);
            float al = g[t] * rsqrtf(var + 1e-5f);
            sAl[t] = al;
            sBe[t] = fmaf(-m, al, be[t]);
        }
    }

    float acc[RPT][4];
#pragma unroll
    for (int i = 0; i < RPT; i++) acc[i][0] = acc[i][1] = acc[i][2] = acc[i][3] = 0.f;

    for (int k0 = 0; k0 < 128; k0 += 64) {
        __syncthreads();
        for (int idx = t; idx < 64 * D / 4; idx += 256)
            reinterpret_cast<float4*>(sW)[idx] =
                reinterpret_cast<const float4*>(W + (size_t)k0 * D)[idx];
        for (int idx = t; idx < 1024; idx += 256) {
            int r = idx & 63, kq = idx >> 6;
            int gr = r0 + r;
            float4 v = make_float4(0.f, 0.f, 0.f, 0.f);
            if (gr < N) v = reinterpret_cast<const float4*>(X + (size_t)gr * 128 + k0)[kq];
            if (FUSE) {
                int kb = k0 + kq * 4;
                v.x = fmaxf(0.f, fmaf(sAl[kb + 0], v.x, sBe[kb + 0]));
                v.y = fmaxf(0.f, fmaf(sAl[kb + 1], v.y, sBe[kb + 1]));
                v.z = fmaxf(0.f, fmaf(sAl[kb + 2], v.z, sBe[kb + 2]));
                v.w = fmaxf(0.f, fmaf(sAl[kb + 3], v.w, sBe[kb + 3]));
            }
            sX[kq * 4 + 0][r] = v.x;
            sX[kq * 4 + 1][r] = v.y;
            sX[kq * 4 + 2][r] = v.z;
            sX[kq * 4 + 3][r] = v.w;
        }
        __syncthreads();
#pragma unroll 4
        for (int kk = 0; kk < 64; kk++) {
            float4 wv = *reinterpret_cast<const float4*>(&sW[kk * D + c0]);
            float xr[RPT];
#pragma unroll
            for (int i = 0; i < RPT; i += 4) {
                float4 xv = *reinterpret_cast<const float4*>(&sX[kk][rr0 + i]);
                xr[i] = xv.x; xr[i + 1] = xv.y; xr[i + 2] = xv.z; xr[i + 3] = xv.w;
            }
#pragma unroll
            for (int i = 0; i < RPT; i++) {
                acc[i][0] = fmaf(xr[i], wv.x, acc[i][0]);
                acc[i][1] = fmaf(xr[i], wv.y, acc[i][1]);
                acc[i][2] = fmaf(xr[i], wv.z, acc[i][2]);
                acc[i][3] = fmaf(xr[i], wv.w, acc[i][3]);
            }
        }
    }
#pragma unroll
    for (int i = 0; i < RPT; i++) {
        int gr = r0 + rr0 + i;
        if (gr < N) {
            float di = dinv[gr];
            float4 v;
            v.x = acc[i][0] * di; v.y = acc[i][1] * di;
            v.z = acc[i][2] * di; v.w = acc[i][3] * di;
            *reinterpret_cast<float4*>(H + (size_t)gr * D + c0) = v;
        }
    }
}

// ------- aggregation: out[i] = dinv[i]*(Hs[i] + sum Hs[col[e]]) + b -------
template <int D>
__global__ __launch_bounds__(256) void k_agg(const float* __restrict__ Hs,
                                             const int* __restrict__ rp,
                                             const int* __restrict__ col,
                                             const float* __restrict__ dinv,
                                             const float* __restrict__ bias,
                                             float* __restrict__ out, int N) {
    int wv = threadIdx.x >> 6, lane = threadIdx.x & 63;
    int i = blockIdx.x * 4 + wv;
    if (i >= N) return;
    int e0 = rp[i], e1 = rp[i + 1];
    float di = dinv[i];
    const float* hi = Hs + (size_t)i * D;
    float a0 = hi[lane];
    float a1 = (D == 128) ? hi[64 + lane] : 0.f;
    int e = e0;
    for (; e + 4 <= e1; e += 4) {
        int s0 = col[e], s1 = col[e + 1], s2 = col[e + 2], s3 = col[e + 3];
        const float* p0 = Hs + (size_t)s0 * D;
        const float* p1 = Hs + (size_t)s1 * D;
        const float* p2 = Hs + (size_t)s2 * D;
        const float* p3 = Hs + (size_t)s3 * D;
        float v00 = p0[lane], v10 = p1[lane], v20 = p2[lane], v30 = p3[lane];
        if (D == 128) {
            float v01 = p0[64 + lane], v11 = p1[64 + lane];
            float v21 = p2[64 + lane], v31 = p3[64 + lane];
            a1 += (v01 + v11) + (v21 + v31);
        }
        a0 += (v00 + v10) + (v20 + v30);
    }
    for (; e < e1; e++) {
        const float* p = Hs + (size_t)col[e] * D;
        a0 += p[lane];
        if (D == 128) a1 += p[64 + lane];
    }
    float* o = out + (size_t)i * D;
    o[lane] = fmaf(di, a0, bias[lane]);
    if (D == 128) o[64 + lane] = fmaf(di, a1, bias[64 + lane]);
}

// ---------------- BN stats (column sum / sumsq) ----------------
__global__ __launch_bounds__(256) void k_stats(const float* __restrict__ X,
                                               float* __restrict__ S, int N) {
    int f = threadIdx.x & 127, h = threadIdx.x >> 7;
    int rend = min(N, (int)(blockIdx.x + 1) * 256);
    float s = 0.f, q = 0.f;
    for (int r = blockIdx.x * 256 + h; r < rend; r += 2) {
        float v = X[(size_t)r * 128 + f];
        s += v;
        q += v * v;
    }
    __shared__ float ls[256], lq[256];
    ls[threadIdx.x] = s;
    lq[threadIdx.x] = q;
    __syncthreads();
    if (h == 0) {
        atomicAdd(&S[f], ls[f] + ls[f + 128]);
        atomicAdd(&S[128 + f], lq[f] + lq[f + 128]);
    }
}

// ---------------- launch ----------------
extern "C" void kernel_launch(void* const* d_in, const int* in_sizes, int n_in,
                              void* d_out, int out_size, void* d_ws, size_t ws_size,
                              hipStream_t stream) {
    const float* x   = (const float*)d_in[0];
    const int*   ew  = (const int*)d_in[1];
    const float* W1  = (const float*)d_in[2];
    const float* b1  = (const float*)d_in[3];
    const float* g1  = (const float*)d_in[4];
    const float* be1 = (const float*)d_in[5];
    const float* W2  = (const float*)d_in[6];
    const float* b2  = (const float*)d_in[7];
    const float* g2  = (const float*)d_in[8];
    const float* be2 = (const float*)d_in[9];
    const float* W3  = (const float*)d_in[10];
    const float* b3  = (const float*)d_in[11];
    const int N = in_sizes[0] / 128;
    const int E = in_sizes[1] / 2;

    char* w = (char*)d_ws;
    size_t off = 0;
    auto alloc = [&](size_t bytes) -> char* {
        char* p = w + off;
        off = (off + bytes + 255) & ~(size_t)255;
        return p;
    };
    int*   src  = (int*)alloc((size_t)E * 4);
    int*   dst  = (int*)alloc((size_t)E * 4);
    int*   col  = (int*)alloc((size_t)E * 4);
    int*   deg  = (int*)alloc((size_t)N * 4);
    int*   rp   = (int*)alloc((size_t)(N + 1) * 4);
    int*   cur  = (int*)alloc((size_t)N * 4);
    float* dinv = (float*)alloc((size_t)N * 4);
    float* S    = (float*)alloc(1024);
    int*   flag = (int*)alloc(256);
    int*   bsum = (int*)alloc(64 * 4);
    float* h    = (float*)alloc((size_t)N * 128 * 4);
    float* t    = (float*)alloc((size_t)N * 128 * 4);
    (void)ws_size; (void)n_in; (void)out_size;

    const int gE = (E + 255) / 256;
    const int gN = (N + 255) / 256;
    const int gM = (N + 63) / 64;
    const int gA = (N + 3) / 4;
    const int gS = (N + 255) / 256;
    const int nb = (N + 1023) / 1024;   // <= 64
    const float invN = 1.0f / (float)N;

    hipMemsetAsync(deg, 0, (size_t)N * 4, stream);
    k_detect<<<1, 256, 0, stream>>>(ew, flag);
    k_convert_hist<<<gE, 256, 0, stream>>>(ew, flag, src, dst, deg, E);
    k_scan1<<<nb, 1024, 0, stream>>>(deg, rp, bsum, N);
    k_scan2<<<1, 64, 0, stream>>>(bsum, rp, nb, N);
    k_fixup<<<gN, 256, 0, stream>>>(rp, cur, bsum, N);
    k_fill<<<gE, 256, 0, stream>>>(src, dst, cur, col, E);
    k_dinv<<<gN, 256, 0, stream>>>(deg, dinv, N);

    // layer 1
    k_mm<128, false><<<gM, 256, 0, stream>>>(x, W1, h, dinv, S, g1, be1, N, invN);
    k_agg<128><<<gA, 256, 0, stream>>>(h, rp, col, dinv, b1, t, N);
    hipMemsetAsync(S, 0, 1024, stream);
    k_stats<<<gS, 256, 0, stream>>>(t, S, N);

    // layer 2 (BN1+ReLU fused into mm load)
    k_mm<128, true><<<gM, 256, 0, stream>>>(t, W2, h, dinv, S, g1, be1, N, invN);
    k_agg<128><<<gA, 256, 0, stream>>>(h, rp, col, dinv, b2, t, N);
    hipMemsetAsync(S, 0, 1024, stream);
    k_stats<<<gS, 256, 0, stream>>>(t, S, N);

    // layer 3 (BN2+ReLU fused, D_OUT = 64, straight to d_out)
    k_mm<64, true><<<gM, 256, 0, stream>>>(t, W3, h, dinv, S, g2, be2, N, invN);
    k_agg<64><<<gA, 256, 0, stream>>>(h, rp, col, dinv, b3, (float*)d_out, N);
}

// Round 3
// 337.691 us; speedup vs baseline: 1.7868x; 1.2229x over previous
//
#include <hip/hip_runtime.h>
#include <hip/hip_fp16.h>
#include <math.h>

struct __align__(16) h2x4 { __half2 a, b, c, d; };

// ---------------- edge dtype sniff ----------------
__global__ void k_detect(const int* __restrict__ ew, int* __restrict__ flag) {
    __shared__ int nz;
    if (threadIdx.x == 0) nz = 0;
    __syncthreads();
    int a = ew[2 * threadIdx.x + 1];
    int b = ew[512 + 2 * threadIdx.x + 1];
    if (a | b) atomicAdd(&nz, 1);
    __syncthreads();
    if (threadIdx.x == 0) *flag = (nz == 0) ? 1 : 0;
}

__global__ void k_hist(const int* __restrict__ ew, const int* __restrict__ flag,
                       int* __restrict__ deg, int E) {
    int e = blockIdx.x * blockDim.x + threadIdx.x;
    if (e >= E) return;
    int d = (*flag) ? ew[2 * E + 2 * e] : ew[E + e];
    atomicAdd(&deg[d], 1);
}

// ---------------- 3-phase parallel exclusive scan of deg -> rp ----------------
__global__ __launch_bounds__(1024) void k_scan1(const int* __restrict__ deg,
                                                int* __restrict__ rp,
                                                int* __restrict__ bsum, int N) {
    __shared__ int buf[1024];
    int t = threadIdx.x;
    int i = blockIdx.x * 1024 + t;
    int v = (i < N) ? deg[i] : 0;
    buf[t] = v;
    __syncthreads();
    int x = v;
    for (int off = 1; off < 1024; off <<= 1) {
        int y = (t >= off) ? buf[t - off] : 0;
        __syncthreads();
        x += y;
        buf[t] = x;
        __syncthreads();
    }
    if (i < N) rp[i] = x - v;
    if (t == 1023) bsum[blockIdx.x] = x;
}

__global__ void k_scan2(int* __restrict__ bsum, int* __restrict__ rp,
                        int nb, int N) {
    int lane = threadIdx.x;
    int v = (lane < nb) ? bsum[lane] : 0;
    int x = v;
    for (int off = 1; off < 64; off <<= 1) {
        int y = __shfl_up(x, off);
        if (lane >= off) x += y;
    }
    if (lane < nb) bsum[lane] = x - v;
    if (lane == 63) rp[N] = x;
}

// fixup + cur init + dinv
__global__ void k_fixup(int* __restrict__ rp, int* __restrict__ cur,
                        const int* __restrict__ bsum, const int* __restrict__ deg,
                        float* __restrict__ dinv, int N) {
    int i = blockIdx.x * blockDim.x + threadIdx.x;
    if (i < N) {
        int r = rp[i] + bsum[i >> 10];
        rp[i] = r;
        cur[i] = r;
        dinv[i] = rsqrtf((float)(deg[i] + 1));  // +1 self loop
    }
}

__global__ void k_fill(const int* __restrict__ ew, const int* __restrict__ flag,
                       int* __restrict__ cur, int* __restrict__ col, int E) {
    int e = blockIdx.x * blockDim.x + threadIdx.x;
    if (e >= E) return;
    int s, d;
    if (*flag) { s = ew[2 * e]; d = ew[2 * E + 2 * e]; }
    else       { s = ew[e];     d = ew[E + e]; }
    int p = atomicAdd(&cur[d], 1);
    col[p] = s;
}

// ------- matmul: H[r][c] = fp16( dinv[r] * sum_k act(X[r][k]) * W[k][c] ) -------
// FUSE=false: X is f32 (layer 1). FUSE=true: X is f16, act = BN+ReLU from S.
template <int D, bool FUSE>
__global__ __launch_bounds__(256) void k_mm(const void* __restrict__ Xv,
                                            const float* __restrict__ W,
                                            __half* __restrict__ H,
                                            const float* __restrict__ dinv,
                                            const float* __restrict__ S,
                                            const float* __restrict__ g,
                                            const float* __restrict__ be,
                                            int N, float invN) {
    constexpr int TXN = D / 4;
    constexpr int TYN = 256 / TXN;
    constexpr int RPT = 64 / TYN;
    __shared__ float sW[64 * D];
    __shared__ float sX[64][68];
    __shared__ float sAl[128], sBe[128];
    const int t = threadIdx.x;
    const int r0 = blockIdx.x * 64;
    const int tx = t % TXN, ty = t / TXN;
    const int c0 = tx * 4, rr0 = ty * RPT;

    if (FUSE && t < 128) {
        float m = S[t] * invN;
        float var = fmaf(-m, m, S[128 + t] * invN);
        float al = g[t] * rsqrtf(var + 1e-5f);
        sAl[t] = al;
        sBe[t] = fmaf(-m, al, be[t]);
    }

    float acc[RPT][4];
#pragma unroll
    for (int i = 0; i < RPT; i++) acc[i][0] = acc[i][1] = acc[i][2] = acc[i][3] = 0.f;

    for (int k0 = 0; k0 < 128; k0 += 64) {
        __syncthreads();
        for (int idx = t; idx < 64 * D / 4; idx += 256)
            reinterpret_cast<float4*>(sW)[idx] =
                reinterpret_cast<const float4*>(W + (size_t)k0 * D)[idx];
        if (!FUSE) {
            const float* Xf = (const float*)Xv;
            for (int idx = t; idx < 1024; idx += 256) {
                int r = idx & 63, kq = idx >> 6;
                int gr = r0 + r;
                float4 v = make_float4(0.f, 0.f, 0.f, 0.f);
                if (gr < N) v = reinterpret_cast<const float4*>(Xf + (size_t)gr * 128 + k0)[kq];
                sX[kq * 4 + 0][r] = v.x;
                sX[kq * 4 + 1][r] = v.y;
                sX[kq * 4 + 2][r] = v.z;
                sX[kq * 4 + 3][r] = v.w;
            }
        } else {
            const __half* Xh = (const __half*)Xv;
            for (int idx = t; idx < 512; idx += 256) {
                int r = idx >> 3, q = idx & 7;      // 8 rows x 128B contiguous per wave
                int gr = r0 + r;
                __half2 z = __floats2half2_rn(0.f, 0.f);
                h2x4 v{z, z, z, z};
                if (gr < N) v = *reinterpret_cast<const h2x4*>(Xh + (size_t)gr * 128 + k0 + q * 8);
                float2 f0 = __half22float2(v.a), f1 = __half22float2(v.b);
                float2 f2 = __half22float2(v.c), f3 = __half22float2(v.d);
                int kb = k0 + q * 8;
                sX[q * 8 + 0][r] = fmaxf(0.f, fmaf(sAl[kb + 0], f0.x, sBe[kb + 0]));
                sX[q * 8 + 1][r] = fmaxf(0.f, fmaf(sAl[kb + 1], f0.y, sBe[kb + 1]));
                sX[q * 8 + 2][r] = fmaxf(0.f, fmaf(sAl[kb + 2], f1.x, sBe[kb + 2]));
                sX[q * 8 + 3][r] = fmaxf(0.f, fmaf(sAl[kb + 3], f1.y, sBe[kb + 3]));
                sX[q * 8 + 4][r] = fmaxf(0.f, fmaf(sAl[kb + 4], f2.x, sBe[kb + 4]));
                sX[q * 8 + 5][r] = fmaxf(0.f, fmaf(sAl[kb + 5], f2.y, sBe[kb + 5]));
                sX[q * 8 + 6][r] = fmaxf(0.f, fmaf(sAl[kb + 6], f3.x, sBe[kb + 6]));
                sX[q * 8 + 7][r] = fmaxf(0.f, fmaf(sAl[kb + 7], f3.y, sBe[kb + 7]));
            }
        }
        __syncthreads();
#pragma unroll 4
        for (int kk = 0; kk < 64; kk++) {
            float4 wv = *reinterpret_cast<const float4*>(&sW[kk * D + c0]);
            float xr[RPT];
#pragma unroll
            for (int i = 0; i < RPT; i += 4) {
                float4 xv = *reinterpret_cast<const float4*>(&sX[kk][rr0 + i]);
                xr[i] = xv.x; xr[i + 1] = xv.y; xr[i + 2] = xv.z; xr[i + 3] = xv.w;
            }
#pragma unroll
            for (int i = 0; i < RPT; i++) {
                acc[i][0] = fmaf(xr[i], wv.x, acc[i][0]);
                acc[i][1] = fmaf(xr[i], wv.y, acc[i][1]);
                acc[i][2] = fmaf(xr[i], wv.z, acc[i][2]);
                acc[i][3] = fmaf(xr[i], wv.w, acc[i][3]);
            }
        }
    }
#pragma unroll
    for (int i = 0; i < RPT; i++) {
        int gr = r0 + rr0 + i;
        if (gr < N) {
            float di = dinv[gr];
            __half2* Hp = reinterpret_cast<__half2*>(H + (size_t)gr * D + c0);
            Hp[0] = __floats2half2_rn(acc[i][0] * di, acc[i][1] * di);
            Hp[1] = __floats2half2_rn(acc[i][2] * di, acc[i][3] * di);
        }
    }
}

// ------- agg D=128: one wave per node, lane = half2 feature pair -------
__global__ __launch_bounds__(256) void k_agg128(const __half2* __restrict__ Hs,
                                                const int* __restrict__ rp,
                                                const int* __restrict__ col,
                                                const float* __restrict__ dinv,
                                                const float* __restrict__ bias,
                                                __half2* __restrict__ out, int N) {
    int wv = threadIdx.x >> 6, lane = threadIdx.x & 63;
    int i = blockIdx.x * 4 + wv;
    if (i >= N) return;
    int e0 = rp[i], e1 = rp[i + 1];
    float di = dinv[i];
    float2 a = __half22float2(Hs[(size_t)i * 64 + lane]);
    int e = e0;
    for (; e + 8 <= e1; e += 8) {
        int s0 = col[e], s1 = col[e + 1], s2 = col[e + 2], s3 = col[e + 3];
        int s4 = col[e + 4], s5 = col[e + 5], s6 = col[e + 6], s7 = col[e + 7];
        float2 v0 = __half22float2(Hs[(size_t)s0 * 64 + lane]);
        float2 v1 = __half22float2(Hs[(size_t)s1 * 64 + lane]);
        float2 v2 = __half22float2(Hs[(size_t)s2 * 64 + lane]);
        float2 v3 = __half22float2(Hs[(size_t)s3 * 64 + lane]);
        float2 v4 = __half22float2(Hs[(size_t)s4 * 64 + lane]);
        float2 v5 = __half22float2(Hs[(size_t)s5 * 64 + lane]);
        float2 v6 = __half22float2(Hs[(size_t)s6 * 64 + lane]);
        float2 v7 = __half22float2(Hs[(size_t)s7 * 64 + lane]);
        a.x += ((v0.x + v1.x) + (v2.x + v3.x)) + ((v4.x + v5.x) + (v6.x + v7.x));
        a.y += ((v0.y + v1.y) + (v2.y + v3.y)) + ((v4.y + v5.y) + (v6.y + v7.y));
    }
    for (; e < e1; e++) {
        float2 v = __half22float2(Hs[(size_t)col[e] * 64 + lane]);
        a.x += v.x; a.y += v.y;
    }
    float2 b = reinterpret_cast<const float2*>(bias)[lane];
    out[(size_t)i * 64 + lane] = __floats2half2_rn(fmaf(di, a.x, b.x), fmaf(di, a.y, b.y));
}

// ------- agg D=64: half-wave (32 lanes) per node, f32 output -------
__global__ __launch_bounds__(256) void k_agg64(const __half2* __restrict__ Hs,
                                               const int* __restrict__ rp,
                                               const int* __restrict__ col,
                                               const float* __restrict__ dinv,
                                               const float* __restrict__ bias,
                                               float* __restrict__ out, int N) {
    int sub = threadIdx.x & 31;
    int i = blockIdx.x * 8 + (threadIdx.x >> 5);
    if (i >= N) return;
    int e0 = rp[i], e1 = rp[i + 1];
    float di = dinv[i];
    float2 a = __half22float2(Hs[(size_t)i * 32 + sub]);
    int e = e0;
    for (; e + 8 <= e1; e += 8) {
        int s0 = col[e], s1 = col[e + 1], s2 = col[e + 2], s3 = col[e + 3];
        int s4 = col[e + 4], s5 = col[e + 5], s6 = col[e + 6], s7 = col[e + 7];
        float2 v0 = __half22float2(Hs[(size_t)s0 * 32 + sub]);
        float2 v1 = __half22float2(Hs[(size_t)s1 * 32 + sub]);
        float2 v2 = __half22float2(Hs[(size_t)s2 * 32 + sub]);
        float2 v3 = __half22float2(Hs[(size_t)s3 * 32 + sub]);
        float2 v4 = __half22float2(Hs[(size_t)s4 * 32 + sub]);
        float2 v5 = __half22float2(Hs[(size_t)s5 * 32 + sub]);
        float2 v6 = __half22float2(Hs[(size_t)s6 * 32 + sub]);
        float2 v7 = __half22float2(Hs[(size_t)s7 * 32 + sub]);
        a.x += ((v0.x + v1.x) + (v2.x + v3.x)) + ((v4.x + v5.x) + (v6.x + v7.x));
        a.y += ((v0.y + v1.y) + (v2.y + v3.y)) + ((v4.y + v5.y) + (v6.y + v7.y));
    }
    for (; e < e1; e++) {
        float2 v = __half22float2(Hs[(size_t)col[e] * 32 + sub]);
        a.x += v.x; a.y += v.y;
    }
    float2 b = reinterpret_cast<const float2*>(bias)[sub];
    float2 o;
    o.x = fmaf(di, a.x, b.x);
    o.y = fmaf(di, a.y, b.y);
    reinterpret_cast<float2*>(out)[(size_t)i * 32 + sub] = o;
}

// ---------------- BN stats over f16 t ----------------
__global__ __launch_bounds__(256) void k_stats(const __half2* __restrict__ X2,
                                               float* __restrict__ S, int N) {
    int cp = threadIdx.x & 63;   // half2 column pair
    int hr = threadIdx.x >> 6;   // 0..3
    int rend = min(N, (int)(blockIdx.x + 1) * 256);
    float2 s = make_float2(0.f, 0.f), q = make_float2(0.f, 0.f);
    for (int r = blockIdx.x * 256 + hr; r < rend; r += 4) {
        float2 v = __half22float2(X2[(size_t)r * 64 + cp]);
        s.x += v.x; s.y += v.y;
        q.x += v.x * v.x; q.y += v.y * v.y;
    }
    __shared__ float ls[4][64][2], lq[4][64][2];
    ls[hr][cp][0] = s.x; ls[hr][cp][1] = s.y;
    lq[hr][cp][0] = q.x; lq[hr][cp][1] = q.y;
    __syncthreads();
    if (hr == 0) {
#pragma unroll
        for (int j = 1; j < 4; j++) {
            s.x += ls[j][cp][0]; s.y += ls[j][cp][1];
            q.x += lq[j][cp][0]; q.y += lq[j][cp][1];
        }
        atomicAdd(&S[2 * cp], s.x);
        atomicAdd(&S[2 * cp + 1], s.y);
        atomicAdd(&S[128 + 2 * cp], q.x);
        atomicAdd(&S[128 + 2 * cp + 1], q.y);
    }
}

// ---------------- launch ----------------
extern "C" void kernel_launch(void* const* d_in, const int* in_sizes, int n_in,
                              void* d_out, int out_size, void* d_ws, size_t ws_size,
                              hipStream_t stream) {
    const float* x   = (const float*)d_in[0];
    const int*   ew  = (const int*)d_in[1];
    const float* W1  = (const float*)d_in[2];
    const float* b1  = (const float*)d_in[3];
    const float* g1  = (const float*)d_in[4];
    const float* be1 = (const float*)d_in[5];
    const float* W2  = (const float*)d_in[6];
    const float* b2  = (const float*)d_in[7];
    const float* g2  = (const float*)d_in[8];
    const float* be2 = (const float*)d_in[9];
    const float* W3  = (const float*)d_in[10];
    const float* b3  = (const float*)d_in[11];
    const int N = in_sizes[0] / 128;
    const int E = in_sizes[1] / 2;

    char* w = (char*)d_ws;
    size_t off = 0;
    auto alloc = [&](size_t bytes) -> char* {
        char* p = w + off;
        off = (off + bytes + 255) & ~(size_t)255;
        return p;
    };
    int*    col  = (int*)alloc((size_t)E * 4);
    int*    deg  = (int*)alloc((size_t)N * 4);
    int*    rp   = (int*)alloc((size_t)(N + 1) * 4);
    int*    cur  = (int*)alloc((size_t)N * 4);
    float*  dinv = (float*)alloc((size_t)N * 4);
    float*  S1   = (float*)alloc(1024);
    float*  S2   = (float*)alloc(1024);
    int*    flag = (int*)alloc(256);
    int*    bsum = (int*)alloc(64 * 4);
    __half* h    = (__half*)alloc((size_t)N * 128 * 2);
    __half* t    = (__half*)alloc((size_t)N * 128 * 2);
    (void)ws_size; (void)n_in; (void)out_size;

    const int gE = (E + 255) / 256;
    const int gN = (N + 255) / 256;
    const int gM = (N + 63) / 64;
    const int gA = (N + 3) / 4;
    const int gA8 = (N + 7) / 8;
    const int gS = (N + 255) / 256;
    const int nb = (N + 1023) / 1024;
    const float invN = 1.0f / (float)N;

    hipMemsetAsync(deg, 0, (size_t)N * 4, stream);
    hipMemsetAsync(S1, 0, 1024, stream);
    hipMemsetAsync(S2, 0, 1024, stream);
    k_detect<<<1, 256, 0, stream>>>(ew, flag);
    k_hist<<<gE, 256, 0, stream>>>(ew, flag, deg, E);
    k_scan1<<<nb, 1024, 0, stream>>>(deg, rp, bsum, N);
    k_scan2<<<1, 64, 0, stream>>>(bsum, rp, nb, N);
    k_fixup<<<gN, 256, 0, stream>>>(rp, cur, bsum, deg, dinv, N);
    k_fill<<<gE, 256, 0, stream>>>(ew, flag, cur, col, E);

    // layer 1
    k_mm<128, false><<<gM, 256, 0, stream>>>(x, W1, h, dinv, S1, g1, be1, N, invN);
    k_agg128<<<gA, 256, 0, stream>>>((const __half2*)h, rp, col, dinv, b1, (__half2*)t, N);
    k_stats<<<gS, 256, 0, stream>>>((const __half2*)t, S1, N);

    // layer 2 (BN1+ReLU fused into mm load)
    k_mm<128, true><<<gM, 256, 0, stream>>>(t, W2, h, dinv, S1, g1, be1, N, invN);
    k_agg128<<<gA, 256, 0, stream>>>((const __half2*)h, rp, col, dinv, b2, (__half2*)t, N);
    k_stats<<<gS, 256, 0, stream>>>((const __half2*)t, S2, N);

    // layer 3 (BN2+ReLU fused, D_OUT = 64, straight to d_out)
    k_mm<64, true><<<gM, 256, 0, stream>>>(t, W3, h, dinv, S2, g2, be2, N, invN);
    k_agg64<<<gA8, 256, 0, stream>>>((const __half2*)h, rp, col, dinv, b3, (float*)d_out, N);
}

// Round 4
// 300.189 us; speedup vs baseline: 2.0100x; 1.1249x over previous
//
#include <hip/hip_runtime.h>
#include <hip/hip_fp16.h>
#include <math.h>

struct __align__(16) h2x4 { __half2 a, b, c, d; };

// Edge access: flag=1 -> int64 storage, flag=0 -> int32.
__device__ inline int edge_src(const int* ew, int f, int e, int E) {
    return f ? ew[2 * e] : ew[e];
}
__device__ inline int edge_dst(const int* ew, int f, int e, int E) {
    return f ? ew[2 * E + 2 * e] : ew[E + e];
}

// ---------------- edge dtype sniff ----------------
__global__ void k_detect(const int* __restrict__ ew, int* __restrict__ flag) {
    __shared__ int nz;
    if (threadIdx.x == 0) nz = 0;
    __syncthreads();
    int a = ew[2 * threadIdx.x + 1];
    int b = ew[512 + 2 * threadIdx.x + 1];
    if (a | b) atomicAdd(&nz, 1);
    __syncthreads();
    if (threadIdx.x == 0) *flag = (nz == 0) ? 1 : 0;
}

// ---------------- bucketed CSR build (buckets of 256 dst nodes, NB<=256) ----------------
__global__ __launch_bounds__(256) void k_bhist(const int* __restrict__ ew,
                                               const int* __restrict__ flag,
                                               int* __restrict__ bsize,
                                               int E, int NB, int chunk) {
    __shared__ int hist[256];
    int t = threadIdx.x;
    hist[t] = 0;
    __syncthreads();
    int f = *flag;
    int c0 = blockIdx.x * chunk, c1 = min(E, c0 + chunk);
    for (int e = c0 + t; e < c1; e += 256)
        atomicAdd(&hist[edge_dst(ew, f, e, E) >> 8], 1);
    __syncthreads();
    if (t < NB && hist[t]) atomicAdd(&bsize[t], hist[t]);
}

__global__ __launch_bounds__(256) void k_bscan(const int* __restrict__ bsize,
                                               int* __restrict__ bbase,
                                               int* __restrict__ bcur, int NB) {
    __shared__ int buf[256];
    int t = threadIdx.x;
    int v = (t < NB) ? bsize[t] : 0;
    buf[t] = v;
    __syncthreads();
    int x = v;
    for (int off = 1; off < 256; off <<= 1) {
        int y = (t >= off) ? buf[t - off] : 0;
        __syncthreads();
        x += y;
        buf[t] = x;
        __syncthreads();
    }
    if (t <= NB) {
        int ex = (t < NB) ? (buf[t] - bsize[t]) : buf[NB ? NB - 1 : 0];
        bbase[t] = ex;
        if (t < NB) bcur[t] = ex;
    }
}

__global__ __launch_bounds__(256) void k_part(const int* __restrict__ ew,
                                              const int* __restrict__ flag,
                                              int* __restrict__ bcur,
                                              int2* __restrict__ be,
                                              int E, int NB, int chunk) {
    __shared__ int histL[256], baseL[256];
    int t = threadIdx.x;
    histL[t] = 0;
    __syncthreads();
    int f = *flag;
    int c0 = blockIdx.x * chunk, c1 = min(E, c0 + chunk);
    for (int e = c0 + t; e < c1; e += 256)
        atomicAdd(&histL[edge_dst(ew, f, e, E) >> 8], 1);
    __syncthreads();
    if (t < NB) {
        int h = histL[t];
        baseL[t] = h ? atomicAdd(&bcur[t], h) : 0;
    }
    __syncthreads();
    histL[t] = 0;
    __syncthreads();
    for (int e = c0 + t; e < c1; e += 256) {
        int s = edge_src(ew, f, e, E);
        int d = edge_dst(ew, f, e, E);
        int b = d >> 8;
        int off = baseL[b] + atomicAdd(&histL[b], 1);
        be[off] = make_int2(s, d);
    }
}

// per-bucket degree count (no global atomics)
__global__ __launch_bounds__(256) void k_bdeg(const int2* __restrict__ be,
                                              const int* __restrict__ bbase,
                                              int* __restrict__ deg, int N) {
    __shared__ int cnt[256];
    int t = threadIdx.x, b = blockIdx.x;
    cnt[t] = 0;
    __syncthreads();
    int p0 = bbase[b], p1 = bbase[b + 1];
    for (int p = p0 + t; p < p1; p += 256)
        atomicAdd(&cnt[be[p].y & 255], 1);
    __syncthreads();
    int i = (b << 8) + t;
    if (i < N) deg[i] = cnt[t];
}

// ---------------- scan deg -> rp ----------------
__global__ __launch_bounds__(1024) void k_scan1(const int* __restrict__ deg,
                                                int* __restrict__ rp,
                                                int* __restrict__ bsum, int N) {
    __shared__ int buf[1024];
    int t = threadIdx.x;
    int i = blockIdx.x * 1024 + t;
    int v = (i < N) ? deg[i] : 0;
    buf[t] = v;
    __syncthreads();
    int x = v;
    for (int off = 1; off < 1024; off <<= 1) {
        int y = (t >= off) ? buf[t - off] : 0;
        __syncthreads();
        x += y;
        buf[t] = x;
        __syncthreads();
    }
    if (i < N) rp[i] = x - v;
    if (t == 1023) bsum[blockIdx.x] = x;
}

__global__ void k_scan2(int* __restrict__ bsum, int* __restrict__ rp,
                        int nb, int N) {
    int lane = threadIdx.x;
    int v = (lane < nb) ? bsum[lane] : 0;
    int x = v;
    for (int off = 1; off < 64; off <<= 1) {
        int y = __shfl_up(x, off);
        if (lane >= off) x += y;
    }
    if (lane < nb) bsum[lane] = x - v;
    if (lane == 63) rp[N] = x;
}

__global__ void k_fixup(int* __restrict__ rp, const int* __restrict__ bsum,
                        const int* __restrict__ deg, float* __restrict__ dinv, int N) {
    int i = blockIdx.x * blockDim.x + threadIdx.x;
    if (i < N) {
        rp[i] += bsum[i >> 10];
        dinv[i] = rsqrtf((float)(deg[i] + 1));  // +1 self loop
    }
}

// fill col: one block per bucket, LDS position counters, private write window
__global__ __launch_bounds__(256) void k_fillb(const int2* __restrict__ be,
                                               const int* __restrict__ bbase,
                                               const int* __restrict__ rp,
                                               int* __restrict__ col, int N) {
    __shared__ int cur[256];
    int t = threadIdx.x, b = blockIdx.x;
    int i = (b << 8) + t;
    cur[t] = (i < N) ? rp[i] : 0;
    __syncthreads();
    int p0 = bbase[b], p1 = bbase[b + 1];
    for (int p = p0 + t; p < p1; p += 256) {
        int2 e = be[p];
        int pos = atomicAdd(&cur[e.y & 255], 1);
        col[pos] = e.x;
    }
}

// ------- matmul: H[r][c] = fp16( dinv[r] * sum_k act(X[r][k]) * W[k][c] ) -------
template <int D, bool FUSE>
__global__ __launch_bounds__(256) void k_mm(const void* __restrict__ Xv,
                                            const float* __restrict__ W,
                                            __half* __restrict__ H,
                                            const float* __restrict__ dinv,
                                            const float* __restrict__ S,
                                            const float* __restrict__ g,
                                            const float* __restrict__ be,
                                            int N, float invN) {
    constexpr int TXN = D / 4;
    constexpr int TYN = 256 / TXN;
    constexpr int RPT = 64 / TYN;
    __shared__ float sW[64 * D];
    __shared__ float sX[64][68];
    __shared__ float sAl[128], sBe[128];
    const int t = threadIdx.x;
    const int r0 = blockIdx.x * 64;
    const int tx = t % TXN, ty = t / TXN;
    const int c0 = tx * 4, rr0 = ty * RPT;

    if (FUSE && t < 128) {
        float m = S[t] * invN;
        float var = fmaf(-m, m, S[128 + t] * invN);
        float al = g[t] * rsqrtf(var + 1e-5f);
        sAl[t] = al;
        sBe[t] = fmaf(-m, al, be[t]);
    }

    float acc[RPT][4];
#pragma unroll
    for (int i = 0; i < RPT; i++) acc[i][0] = acc[i][1] = acc[i][2] = acc[i][3] = 0.f;

    for (int k0 = 0; k0 < 128; k0 += 64) {
        __syncthreads();
        for (int idx = t; idx < 64 * D / 4; idx += 256)
            reinterpret_cast<float4*>(sW)[idx] =
                reinterpret_cast<const float4*>(W + (size_t)k0 * D)[idx];
        if (!FUSE) {
            const float* Xf = (const float*)Xv;
            for (int idx = t; idx < 1024; idx += 256) {
                int r = idx & 63, kq = idx >> 6;
                int gr = r0 + r;
                float4 v = make_float4(0.f, 0.f, 0.f, 0.f);
                if (gr < N) v = reinterpret_cast<const float4*>(Xf + (size_t)gr * 128 + k0)[kq];
                sX[kq * 4 + 0][r] = v.x;
                sX[kq * 4 + 1][r] = v.y;
                sX[kq * 4 + 2][r] = v.z;
                sX[kq * 4 + 3][r] = v.w;
            }
        } else {
            const __half* Xh = (const __half*)Xv;
            for (int idx = t; idx < 512; idx += 256) {
                int r = idx >> 3, q = idx & 7;
                int gr = r0 + r;
                __half2 z = __floats2half2_rn(0.f, 0.f);
                h2x4 v{z, z, z, z};
                if (gr < N) v = *reinterpret_cast<const h2x4*>(Xh + (size_t)gr * 128 + k0 + q * 8);
                float2 f0 = __half22float2(v.a), f1 = __half22float2(v.b);
                float2 f2 = __half22float2(v.c), f3 = __half22float2(v.d);
                int kb = k0 + q * 8;
                sX[q * 8 + 0][r] = fmaxf(0.f, fmaf(sAl[kb + 0], f0.x, sBe[kb + 0]));
                sX[q * 8 + 1][r] = fmaxf(0.f, fmaf(sAl[kb + 1], f0.y, sBe[kb + 1]));
                sX[q * 8 + 2][r] = fmaxf(0.f, fmaf(sAl[kb + 2], f1.x, sBe[kb + 2]));
                sX[q * 8 + 3][r] = fmaxf(0.f, fmaf(sAl[kb + 3], f1.y, sBe[kb + 3]));
                sX[q * 8 + 4][r] = fmaxf(0.f, fmaf(sAl[kb + 4], f2.x, sBe[kb + 4]));
                sX[q * 8 + 5][r] = fmaxf(0.f, fmaf(sAl[kb + 5], f2.y, sBe[kb + 5]));
                sX[q * 8 + 6][r] = fmaxf(0.f, fmaf(sAl[kb + 6], f3.x, sBe[kb + 6]));
                sX[q * 8 + 7][r] = fmaxf(0.f, fmaf(sAl[kb + 7], f3.y, sBe[kb + 7]));
            }
        }
        __syncthreads();
#pragma unroll 4
        for (int kk = 0; kk < 64; kk++) {
            float4 wv = *reinterpret_cast<const float4*>(&sW[kk * D + c0]);
            float xr[RPT];
#pragma unroll
            for (int i = 0; i < RPT; i += 4) {
                float4 xv = *reinterpret_cast<const float4*>(&sX[kk][rr0 + i]);
                xr[i] = xv.x; xr[i + 1] = xv.y; xr[i + 2] = xv.z; xr[i + 3] = xv.w;
            }
#pragma unroll
            for (int i = 0; i < RPT; i++) {
                acc[i][0] = fmaf(xr[i], wv.x, acc[i][0]);
                acc[i][1] = fmaf(xr[i], wv.y, acc[i][1]);
                acc[i][2] = fmaf(xr[i], wv.z, acc[i][2]);
                acc[i][3] = fmaf(xr[i], wv.w, acc[i][3]);
            }
        }
    }
#pragma unroll
    for (int i = 0; i < RPT; i++) {
        int gr = r0 + rr0 + i;
        if (gr < N) {
            float di = dinv[gr];
            __half2* Hp = reinterpret_cast<__half2*>(H + (size_t)gr * D + c0);
            Hp[0] = __floats2half2_rn(acc[i][0] * di, acc[i][1] * di);
            Hp[1] = __floats2half2_rn(acc[i][2] * di, acc[i][3] * di);
        }
    }
}

// ------- agg D=128: one wave per node, lane = half2 feature pair -------
__global__ __launch_bounds__(256) void k_agg128(const __half2* __restrict__ Hs,
                                                const int* __restrict__ rp,
                                                const int* __restrict__ col,
                                                const float* __restrict__ dinv,
                                                const float* __restrict__ bias,
                                                __half2* __restrict__ out, int N) {
    int wv = threadIdx.x >> 6, lane = threadIdx.x & 63;
    int i = blockIdx.x * 4 + wv;
    if (i >= N) return;
    int e0 = rp[i], e1 = rp[i + 1];
    float di = dinv[i];
    float2 a = __half22float2(Hs[(size_t)i * 64 + lane]);
    int e = e0;
    for (; e + 8 <= e1; e += 8) {
        int s0 = col[e], s1 = col[e + 1], s2 = col[e + 2], s3 = col[e + 3];
        int s4 = col[e + 4], s5 = col[e + 5], s6 = col[e + 6], s7 = col[e + 7];
        float2 v0 = __half22float2(Hs[(size_t)s0 * 64 + lane]);
        float2 v1 = __half22float2(Hs[(size_t)s1 * 64 + lane]);
        float2 v2 = __half22float2(Hs[(size_t)s2 * 64 + lane]);
        float2 v3 = __half22float2(Hs[(size_t)s3 * 64 + lane]);
        float2 v4 = __half22float2(Hs[(size_t)s4 * 64 + lane]);
        float2 v5 = __half22float2(Hs[(size_t)s5 * 64 + lane]);
        float2 v6 = __half22float2(Hs[(size_t)s6 * 64 + lane]);
        float2 v7 = __half22float2(Hs[(size_t)s7 * 64 + lane]);
        a.x += ((v0.x + v1.x) + (v2.x + v3.x)) + ((v4.x + v5.x) + (v6.x + v7.x));
        a.y += ((v0.y + v1.y) + (v2.y + v3.y)) + ((v4.y + v5.y) + (v6.y + v7.y));
    }
    for (; e < e1; e++) {
        float2 v = __half22float2(Hs[(size_t)col[e] * 64 + lane]);
        a.x += v.x; a.y += v.y;
    }
    float2 b = reinterpret_cast<const float2*>(bias)[lane];
    out[(size_t)i * 64 + lane] = __floats2half2_rn(fmaf(di, a.x, b.x), fmaf(di, a.y, b.y));
}

// ------- agg D=64: half-wave per node, f32 output -------
__global__ __launch_bounds__(256) void k_agg64(const __half2* __restrict__ Hs,
                                               const int* __restrict__ rp,
                                               const int* __restrict__ col,
                                               const float* __restrict__ dinv,
                                               const float* __restrict__ bias,
                                               float* __restrict__ out, int N) {
    int sub = threadIdx.x & 31;
    int i = blockIdx.x * 8 + (threadIdx.x >> 5);
    if (i >= N) return;
    int e0 = rp[i], e1 = rp[i + 1];
    float di = dinv[i];
    float2 a = __half22float2(Hs[(size_t)i * 32 + sub]);
    int e = e0;
    for (; e + 8 <= e1; e += 8) {
        int s0 = col[e], s1 = col[e + 1], s2 = col[e + 2], s3 = col[e + 3];
        int s4 = col[e + 4], s5 = col[e + 5], s6 = col[e + 6], s7 = col[e + 7];
        float2 v0 = __half22float2(Hs[(size_t)s0 * 32 + sub]);
        float2 v1 = __half22float2(Hs[(size_t)s1 * 32 + sub]);
        float2 v2 = __half22float2(Hs[(size_t)s2 * 32 + sub]);
        float2 v3 = __half22float2(Hs[(size_t)s3 * 32 + sub]);
        float2 v4 = __half22float2(Hs[(size_t)s4 * 32 + sub]);
        float2 v5 = __half22float2(Hs[(size_t)s5 * 32 + sub]);
        float2 v6 = __half22float2(Hs[(size_t)s6 * 32 + sub]);
        float2 v7 = __half22float2(Hs[(size_t)s7 * 32 + sub]);
        a.x += ((v0.x + v1.x) + (v2.x + v3.x)) + ((v4.x + v5.x) + (v6.x + v7.x));
        a.y += ((v0.y + v1.y) + (v2.y + v3.y)) + ((v4.y + v5.y) + (v6.y + v7.y));
    }
    for (; e < e1; e++) {
        float2 v = __half22float2(Hs[(size_t)col[e] * 32 + sub]);
        a.x += v.x; a.y += v.y;
    }
    float2 b = reinterpret_cast<const float2*>(bias)[sub];
    float2 o;
    o.x = fmaf(di, a.x, b.x);
    o.y = fmaf(di, a.y, b.y);
    reinterpret_cast<float2*>(out)[(size_t)i * 32 + sub] = o;
}

// ---------------- BN stats over f16 t ----------------
__global__ __launch_bounds__(256) void k_stats(const __half2* __restrict__ X2,
                                               float* __restrict__ S, int N) {
    int cp = threadIdx.x & 63;
    int hr = threadIdx.x >> 6;
    int rend = min(N, (int)(blockIdx.x + 1) * 256);
    float2 s = make_float2(0.f, 0.f), q = make_float2(0.f, 0.f);
    for (int r = blockIdx.x * 256 + hr; r < rend; r += 4) {
        float2 v = __half22float2(X2[(size_t)r * 64 + cp]);
        s.x += v.x; s.y += v.y;
        q.x += v.x * v.x; q.y += v.y * v.y;
    }
    __shared__ float ls[4][64][2], lq[4][64][2];
    ls[hr][cp][0] = s.x; ls[hr][cp][1] = s.y;
    lq[hr][cp][0] = q.x; lq[hr][cp][1] = q.y;
    __syncthreads();
    if (hr == 0) {
#pragma unroll
        for (int j = 1; j < 4; j++) {
            s.x += ls[j][cp][0]; s.y += ls[j][cp][1];
            q.x += lq[j][cp][0]; q.y += lq[j][cp][1];
        }
        atomicAdd(&S[2 * cp], s.x);
        atomicAdd(&S[2 * cp + 1], s.y);
        atomicAdd(&S[128 + 2 * cp], q.x);
        atomicAdd(&S[128 + 2 * cp + 1], q.y);
    }
}

// ---------------- launch ----------------
extern "C" void kernel_launch(void* const* d_in, const int* in_sizes, int n_in,
                              void* d_out, int out_size, void* d_ws, size_t ws_size,
                              hipStream_t stream) {
    const float* x   = (const float*)d_in[0];
    const int*   ew  = (const int*)d_in[1];
    const float* W1  = (const float*)d_in[2];
    const float* b1  = (const float*)d_in[3];
    const float* g1  = (const float*)d_in[4];
    const float* be1 = (const float*)d_in[5];
    const float* W2  = (const float*)d_in[6];
    const float* b2  = (const float*)d_in[7];
    const float* g2  = (const float*)d_in[8];
    const float* be2 = (const float*)d_in[9];
    const float* W3  = (const float*)d_in[10];
    const float* b3  = (const float*)d_in[11];
    const int N = in_sizes[0] / 128;
    const int E = in_sizes[1] / 2;
    const int NB = (N + 255) >> 8;       // buckets of 256 dst nodes (N<=65536)

    char* w = (char*)d_ws;
    size_t off = 0;
    auto alloc = [&](size_t bytes) -> char* {
        char* p = w + off;
        off = (off + bytes + 255) & ~(size_t)255;
        return p;
    };
    int*    col   = (int*)alloc((size_t)E * 4);
    int2*   be    = (int2*)alloc((size_t)E * 8);
    int*    deg   = (int*)alloc((size_t)N * 4);
    int*    rp    = (int*)alloc((size_t)(N + 1) * 4);
    float*  dinv  = (float*)alloc((size_t)N * 4);
    float*  S1    = (float*)alloc(1024);
    float*  S2    = (float*)alloc(1024);
    int*    flag  = (int*)alloc(256);
    int*    bsum  = (int*)alloc(64 * 4);
    int*    bsize = (int*)alloc(257 * 4);
    int*    bbase = (int*)alloc(257 * 4);
    int*    bcur  = (int*)alloc(257 * 4);
    __half* h     = (__half*)alloc((size_t)N * 128 * 2);
    __half* t     = (__half*)alloc((size_t)N * 128 * 2);
    (void)ws_size; (void)n_in; (void)out_size;

    const int gN = (N + 255) / 256;
    const int gM = (N + 63) / 64;
    const int gA = (N + 3) / 4;
    const int gA8 = (N + 7) / 8;
    const int gS = (N + 255) / 256;
    const int nb = (N + 1023) / 1024;
    const int PB = 128;                       // partition blocks
    const int chunk = (E + PB - 1) / PB;
    const float invN = 1.0f / (float)N;

    hipMemsetAsync(bsize, 0, 257 * 4, stream);
    hipMemsetAsync(S1, 0, 1024, stream);
    hipMemsetAsync(S2, 0, 1024, stream);
    k_detect<<<1, 256, 0, stream>>>(ew, flag);
    k_bhist<<<PB, 256, 0, stream>>>(ew, flag, bsize, E, NB, chunk);
    k_bscan<<<1, 256, 0, stream>>>(bsize, bbase, bcur, NB);
    k_part<<<PB, 256, 0, stream>>>(ew, flag, bcur, be, E, NB, chunk);
    k_bdeg<<<NB, 256, 0, stream>>>(be, bbase, deg, N);
    k_scan1<<<nb, 1024, 0, stream>>>(deg, rp, bsum, N);
    k_scan2<<<1, 64, 0, stream>>>(bsum, rp, nb, N);
    k_fixup<<<gN, 256, 0, stream>>>(rp, bsum, deg, dinv, N);
    k_fillb<<<NB, 256, 0, stream>>>(be, bbase, rp, col, N);

    // layer 1
    k_mm<128, false><<<gM, 256, 0, stream>>>(x, W1, h, dinv, S1, g1, be1, N, invN);
    k_agg128<<<gA, 256, 0, stream>>>((const __half2*)h, rp, col, dinv, b1, (__half2*)t, N);
    k_stats<<<gS, 256, 0, stream>>>((const __half2*)t, S1, N);

    // layer 2 (BN1+ReLU fused into mm load)
    k_mm<128, true><<<gM, 256, 0, stream>>>(t, W2, h, dinv, S1, g1, be1, N, invN);
    k_agg128<<<gA, 256, 0, stream>>>((const __half2*)h, rp, col, dinv, b2, (__half2*)t, N);
    k_stats<<<gS, 256, 0, stream>>>((const __half2*)t, S2, N);

    // layer 3 (BN2+ReLU fused, D_OUT = 64, straight to d_out)
    k_mm<64, true><<<gM, 256, 0, stream>>>(t, W3, h, dinv, S2, g2, be2, N, invN);
    k_agg64<<<gA8, 256, 0, stream>>>((const __half2*)h, rp, col, dinv, b3, (float*)d_out, N);
}